// Round 1
// 5949.020 us; speedup vs baseline: 1.4462x; 1.4462x over previous
//
#include <hip/hip_runtime.h>

#define B_SZ   256
#define D_IN   512
#define T_LEN  512
#define H_DIM  1024
#define KTOT   1536   // H_DIM + D_IN
#define NCLASS 1000

using half8   = __attribute__((ext_vector_type(8))) _Float16;
using floatx4 = __attribute__((ext_vector_type(4))) float;

__device__ __forceinline__ float ftanh(float x) {
    x = fminf(fmaxf(x, -20.f), 20.f);
    float e = __expf(2.f * x);
    return (e - 1.f) / (e + 1.f);
}

// ---------------------------------------------------------------------------
// Transpose x [B][D][T] fp32 -> xT [T][B][D] f16 (so step-kernel A-loads are
// contiguous in the contraction dim).
// ---------------------------------------------------------------------------
__global__ void k_transpose_x(const float* __restrict__ x, _Float16* __restrict__ xT) {
    __shared__ float tile[32][33];
    int b = blockIdx.z, d0 = blockIdx.y * 32, t0 = blockIdx.x * 32;
    int tx = threadIdx.x, ty = threadIdx.y;   // 32 x 8
    const float* xp = x + ((size_t)b * D_IN + d0) * T_LEN + t0;
#pragma unroll
    for (int i = 0; i < 4; ++i)
        tile[ty + i * 8][tx] = xp[(size_t)(ty + i * 8) * T_LEN + tx];
    __syncthreads();
#pragma unroll
    for (int i = 0; i < 4; ++i) {
        int t = t0 + ty + i * 8;
        xT[((size_t)t * B_SZ + b) * D_IN + d0 + tx] = (_Float16)tile[tx][ty + i * 8];
    }
}

// ---------------------------------------------------------------------------
// Build WcatT [4096][1536] f16, column-major weights: WcatT[n][k].
// n = gate*1024 + j, gate order g,f,i,o.  k<1024 -> Wh[k][j], k>=1024 -> Wx[k-1024][j].
// ---------------------------------------------------------------------------
__global__ void k_build_wcat(const float* __restrict__ Wgh, const float* __restrict__ Wfh,
                             const float* __restrict__ Wih, const float* __restrict__ Woh,
                             const float* __restrict__ Wgx, const float* __restrict__ Wfx,
                             const float* __restrict__ Wix, const float* __restrict__ Wox,
                             _Float16* __restrict__ WcatT) {
    int src = blockIdx.z;                 // 0..3 = Wh g,f,i,o ; 4..7 = Wx g,f,i,o
    int kmax = (src < 4) ? 1024 : 512;
    int koff = (src < 4) ? 0 : 1024;
    int gi = src & 3;
    const float* W;
    switch (src) {
        case 0: W = Wgh; break; case 1: W = Wfh; break;
        case 2: W = Wih; break; case 3: W = Woh; break;
        case 4: W = Wgx; break; case 5: W = Wfx; break;
        case 6: W = Wix; break; default: W = Wox; break;
    }
    int k0 = blockIdx.y * 32;
    if (k0 >= kmax) return;
    int j0 = blockIdx.x * 32;
    __shared__ float tile[32][33];
    int tx = threadIdx.x, ty = threadIdx.y;   // 32 x 8
#pragma unroll
    for (int i = 0; i < 4; ++i)
        tile[ty + i * 8][tx] = W[(size_t)(k0 + ty + i * 8) * 1024 + j0 + tx];
    __syncthreads();
#pragma unroll
    for (int i = 0; i < 4; ++i) {
        int n = gi * 1024 + j0 + ty + i * 8;
        WcatT[(size_t)n * KTOT + koff + k0 + tx] = (_Float16)tile[tx][ty + i * 8];
    }
}

// ---------------------------------------------------------------------------
// Init: zero c, zero h buffer 0, build concatenated bias [4096] (g,f,i,o).
// (ws is re-poisoned to 0xAA before every timed call, so this runs every call.)
// ---------------------------------------------------------------------------
__global__ void k_init(float* __restrict__ c, unsigned int* __restrict__ h0u,
                       float* __restrict__ bias,
                       const float* __restrict__ bg, const float* __restrict__ bf,
                       const float* __restrict__ bi, const float* __restrict__ bo) {
    int idx = blockIdx.x * 256 + threadIdx.x;          // grid 1024 -> 262144
    if (idx < 262144) c[idx] = 0.f;
    if (idx < 131072) h0u[idx] = 0u;                   // 262144 halves
    if (idx < 4096) {
        int gi = idx >> 10, j = idx & 1023;
        float v = (gi == 0) ? bg[j] : (gi == 1) ? bf[j] : (gi == 2) ? bi[j] : bo[j];
        bias[idx] = v;
    }
}

// ---------------------------------------------------------------------------
// Raw barrier: explicit lgkmcnt(0) gives cross-wave LDS-write visibility, the
// raw s_barrier does NOT drain vmcnt -> in-flight global prefetch survives.
// (__syncthreads would emit s_waitcnt vmcnt(0) and kill the pipeline.)
// ---------------------------------------------------------------------------
__device__ __forceinline__ void bar() {
    asm volatile("s_waitcnt lgkmcnt(0)" ::: "memory");
    __builtin_amdgcn_s_barrier();
    asm volatile("" ::: "memory");
}

// ---------------------------------------------------------------------------
// One recurrence step. Grid 256 x 256 threads (4 waves), 1 block/CU.
// Block owns 64 batch rows (rg) x 16 h-cols (cg); wave w = rows r0+16w..+16.
// K = 1536 (1024 h + 512 x), 24 chunks of 64, double-buffered LDS with
// distance-2 register prefetch; one raw barrier per chunk.
// ---------------------------------------------------------------------------
__global__ __launch_bounds__(256)
void k_step(const _Float16* __restrict__ h_in, _Float16* __restrict__ h_out,
            float* __restrict__ h_f32, float* __restrict__ c_st,
            const _Float16* __restrict__ xTt, const _Float16* __restrict__ WcatT,
            const float* __restrict__ bias, int is_last) {
    __shared__ __align__(16) _Float16 As[2][64][72];   // 64 rows x 64 k (+8 pad)
    __shared__ __align__(16) _Float16 Bs[2][64][72];   // 64 n (gate*16+c) x 64 k

    int bid = blockIdx.x;
    int xcd = bid & 7, idx = bid >> 3;
    int cg = xcd * 8 + (idx & 7);     // [0,64) h-col group -> same-XCD L2 locality
    int rg = idx >> 3;                // [0,4)  batch group (64 rows)
    int r0 = rg * 64, hc0 = cg * 16;

    int tid = threadIdx.x, wave = tid >> 6, lane = tid & 63;

    floatx4 acc[4];
#pragma unroll
    for (int g = 0; g < 4; ++g) acc[g] = (floatx4){0.f, 0.f, 0.f, 0.f};

    // staging decomposition: 64 rows x 64 halves, 256 threads x 32 B
    int arow = tid >> 2, ac16 = (tid & 3) << 4;
    const _Float16* hbase = h_in + (size_t)(r0 + arow) * H_DIM + ac16;
    const _Float16* xbase = xTt + (size_t)(r0 + arow) * D_IN + ac16;
    const _Float16* bbase = WcatT +
        (size_t)((arow >> 4) * 1024 + hc0 + (arow & 15)) * KTOT + ac16;

    int am = wave * 16 + (lane & 15);
    int koffA = (lane >> 4) << 3;
    int ncol = lane & 15;

#define LOADSET(A0, A1, B0, B1, c) do {                                         \
        const _Float16* _sa = ((c) < 16) ? (hbase + ((c) << 6))                 \
                                         : (xbase + (((c) - 16) << 6));         \
        A0 = ((const uint4*)_sa)[0]; A1 = ((const uint4*)_sa)[1];               \
        const _Float16* _sb = bbase + ((c) << 6);                               \
        B0 = ((const uint4*)_sb)[0]; B1 = ((const uint4*)_sb)[1];               \
    } while (0)

#define STORESET(A0, A1, B0, B1, buf) do {                                      \
        *(uint4*)&As[buf][arow][ac16]     = A0;                                 \
        *(uint4*)&As[buf][arow][ac16 + 8] = A1;                                 \
        *(uint4*)&Bs[buf][arow][ac16]     = B0;                                 \
        *(uint4*)&Bs[buf][arow][ac16 + 8] = B1;                                 \
    } while (0)

#define MFMA_CHUNK(buf) do {                                                    \
        _Pragma("unroll")                                                       \
        for (int kk = 0; kk < 2; ++kk) {                                        \
            half8 af = *(const half8*)&As[buf][am][kk * 32 + koffA];            \
            _Pragma("unroll")                                                   \
            for (int g = 0; g < 4; ++g) {                                       \
                half8 bf8 = *(const half8*)&Bs[buf][g * 16 + ncol][kk * 32 + koffA]; \
                acc[g] = __builtin_amdgcn_mfma_f32_16x16x32_f16(af, bf8, acc[g], 0, 0, 0); \
            }                                                                   \
        }                                                                       \
    } while (0)

    uint4 aA0, aA1, bA0, bA1;   // prefetch set A (even-chunk stream: 0,2,4,..)
    uint4 aB0, aB1, bB0, bB1;   // prefetch set B (odd-chunk stream: 1,3,5,..)

    // prologue: buf0 <- chunk0; setB = chunk1 in flight; setA = chunk2 in flight
    LOADSET(aA0, aA1, bA0, bA1, 0);
    LOADSET(aB0, aB1, bB0, bB1, 1);
    STORESET(aA0, aA1, bA0, bA1, 0);     // compiler emits counted vmcnt(4)
    LOADSET(aA0, aA1, bA0, bA1, 2);
    bar();

#pragma unroll
    for (int cc = 0; cc < 12; ++cc) {
        // invariant: buf0 = chunk 2cc (ready); setB = 2cc+1, setA = 2cc+2 (in flight)
        STORESET(aB0, aB1, bB0, bB1, 1);                 // chunk 2cc+1 -> buf1
        MFMA_CHUNK(0);                                    // compute chunk 2cc
        if (2 * cc + 3 < 24) LOADSET(aB0, aB1, bB0, bB1, 2 * cc + 3);
        bar();
        if (2 * cc + 2 < 24) STORESET(aA0, aA1, bA0, bA1, 0);  // chunk 2cc+2 -> buf0
        MFMA_CHUNK(1);                                    // compute chunk 2cc+1
        if (2 * cc + 4 < 24) LOADSET(aA0, aA1, bA0, bA1, 2 * cc + 4);
        bar();
    }

#undef LOADSET
#undef STORESET
#undef MFMA_CHUNK

    // Epilogue: C/D layout col=lane&15, row=(lane>>4)*4+r  [verified m89]
    int q = lane >> 4, col = lane & 15;
    int gcol = hc0 + col;
    float bg_ = bias[gcol], bf_ = bias[1024 + gcol];
    float bi_ = bias[2048 + gcol], bo_ = bias[3072 + gcol];
#pragma unroll
    for (int r = 0; r < 4; ++r) {
        int grow = r0 + wave * 16 + q * 4 + r;
        size_t off = (size_t)grow * H_DIM + gcol;
        float g  = ftanh(acc[0][r] + bg_);
        float f  = ftanh(acc[1][r] + bf_);
        float ii = ftanh(acc[2][r] + bi_);
        float o  = ftanh(acc[3][r] + bo_);
        float cn = g * ii + c_st[off] * f;
        c_st[off] = cn;
        float hn = ftanh(cn) * o;
        h_out[off] = (_Float16)hn;
        if (is_last) h_f32[off] = hn;
    }
}

// ---------------------------------------------------------------------------
// logits[256][1024(pad)] = h @ W_ph + b_p   (fp32 vector; tiny GEMM)
// grid (16 col-tiles x 8 row-tiles), 256 threads; WG tile 32 rows x 64 cols
// ---------------------------------------------------------------------------
__global__ void k_logits(const float* __restrict__ h, const float* __restrict__ Wp,
                         const float* __restrict__ bp, float* __restrict__ logits) {
    __shared__ float hs[32][65];
    int r0 = blockIdx.y * 32;
    int c0 = blockIdx.x * 64;
    int tid = threadIdx.x;
    int wave = tid >> 6, tx = tid & 63;
    int col = c0 + tx;
    float s[8];
#pragma unroll
    for (int i = 0; i < 8; ++i) s[i] = 0.f;
    for (int kc = 0; kc < 16; ++kc) {
        int k0 = kc * 64;
#pragma unroll
        for (int i = 0; i < 8; ++i) {
            int idx = tid + i * 256;
            hs[idx >> 6][idx & 63] = h[(size_t)(r0 + (idx >> 6)) * H_DIM + k0 + (idx & 63)];
        }
        __syncthreads();
        if (col < NCLASS) {
            for (int kk = 0; kk < 64; ++kk) {
                float wv = Wp[(size_t)(k0 + kk) * NCLASS + col];
#pragma unroll
                for (int rr = 0; rr < 8; ++rr) s[rr] += hs[wave * 8 + rr][kk] * wv;
            }
        }
        __syncthreads();
    }
    if (col < NCLASS) {
#pragma unroll
        for (int rr = 0; rr < 8; ++rr)
            logits[(size_t)(r0 + wave * 8 + rr) * 1024 + col] = s[rr] + bp[col];
    }
}

// ---------------------------------------------------------------------------
// Row softmax over 1000 classes -> d_out [256][1000] fp32
// ---------------------------------------------------------------------------
__global__ void k_softmax(const float* __restrict__ logits, float* __restrict__ out) {
    __shared__ float red[256];
    int row = blockIdx.x, tid = threadIdx.x;
    float v[4];
    float mx = -1e30f;
#pragma unroll
    for (int i = 0; i < 4; ++i) {
        int c = tid + i * 256;
        float z = (c < NCLASS) ? logits[(size_t)row * 1024 + c] : -1e30f;
        v[i] = z;
        mx = fmaxf(mx, z);
    }
    red[tid] = mx; __syncthreads();
    for (int s = 128; s > 0; s >>= 1) {
        if (tid < s) red[tid] = fmaxf(red[tid], red[tid + s]);
        __syncthreads();
    }
    mx = red[0]; __syncthreads();
    float sum = 0.f;
#pragma unroll
    for (int i = 0; i < 4; ++i) {
        int c = tid + i * 256;
        v[i] = (c < NCLASS) ? __expf(v[i] - mx) : 0.f;
        sum += v[i];
    }
    red[tid] = sum; __syncthreads();
    for (int s = 128; s > 0; s >>= 1) {
        if (tid < s) red[tid] += red[tid + s];
        __syncthreads();
    }
    float inv = 1.f / red[0];
#pragma unroll
    for (int i = 0; i < 4; ++i) {
        int c = tid + i * 256;
        if (c < NCLASS) out[(size_t)row * NCLASS + c] = v[i] * inv;
    }
}

// ---------------------------------------------------------------------------
extern "C" void kernel_launch(void* const* d_in, const int* in_sizes, int n_in,
                              void* d_out, int out_size, void* d_ws, size_t ws_size,
                              hipStream_t stream) {
    const float* x   = (const float*)d_in[0];
    const float* Wfx = (const float*)d_in[1];
    const float* Wfh = (const float*)d_in[2];
    const float* Wgx = (const float*)d_in[3];
    const float* Wgh = (const float*)d_in[4];
    const float* Wix = (const float*)d_in[5];
    const float* Wih = (const float*)d_in[6];
    const float* Wox = (const float*)d_in[7];
    const float* Woh = (const float*)d_in[8];
    const float* Wph = (const float*)d_in[9];
    const float* bf  = (const float*)d_in[10];
    const float* bg  = (const float*)d_in[11];
    const float* bi  = (const float*)d_in[12];
    const float* bo  = (const float*)d_in[13];
    const float* bp  = (const float*)d_in[14];
    float* outp = (float*)d_out;

    char* ws = (char*)d_ws;
    // workspace layout (all offsets 256B-aligned); total ~144 MB
    _Float16* xT    = (_Float16*)(ws);                       // 512*256*512*2   = 134217728
    _Float16* WcatT = (_Float16*)(ws + 134217728);           // 4096*1536*2     = 12582912
    float*    bias  = (float*)   (ws + 146800640);           // 4096*4          = 16384
    _Float16* hb0   = (_Float16*)(ws + 146817024);           // 256*1024*2      = 524288
    _Float16* hb1   = (_Float16*)(ws + 147341312);           // 524288
    float*    c_st  = (float*)   (ws + 147865600);           // 256*1024*4      = 1048576
    float*    hf32  = (float*)   (ws + 148914176);           // 1048576
    float*    logit = (float*)   (ws + 149962752);           // 256*1024*4      = 1048576

    k_transpose_x<<<dim3(16, 16, 256), dim3(32, 8), 0, stream>>>(x, xT);
    k_build_wcat<<<dim3(32, 32, 8), dim3(32, 8), 0, stream>>>(
        Wgh, Wfh, Wih, Woh, Wgx, Wfx, Wix, Wox, WcatT);
    k_init<<<1024, 256, 0, stream>>>(c_st, (unsigned int*)hb0, bias, bg, bf, bi, bo);

    for (int t = 0; t < T_LEN; ++t) {
        const _Float16* hin = (t & 1) ? hb1 : hb0;
        _Float16*       hout = (t & 1) ? hb0 : hb1;
        k_step<<<256, 256, 0, stream>>>(hin, hout, hf32, c_st,
                                        xT + (size_t)t * B_SZ * D_IN, WcatT, bias,
                                        (t == T_LEN - 1) ? 1 : 0);
    }

    k_logits<<<dim3(16, 8), 256, 0, stream>>>(hf32, Wph, bp, logit);
    k_softmax<<<256, 256, 0, stream>>>(logit, outp);
}